// Round 1
// baseline (10222.167 us; speedup 1.0000x reference)
//
#include <hip/hip_runtime.h>
#include <math.h>

#define S_TOT 64
#define CIN   3
#define CH    32
#define H     256
#define W     256
#define WF    129   // W/2+1

// complex rotation update: (cr,ci) *= (wr,wi)
#define ROT(cr, ci, wr, wi) { float _t = fmaf((cr),(wr), -((ci)*(wi))); (ci) = fmaf((cr),(wi), (ci)*(wr)); (cr) = _t; }

// ---------------- Kernel 1: conv1 (3->32, 3x3 SAME) + ReLU ----------------
__global__ __launch_bounds__(256)
void k_conv1(const float* __restrict__ z, const float* __restrict__ w1,
             const float* __restrict__ b1, float* __restrict__ x1,
             int s0, int sch)
{
  int idx = blockIdx.x * 256 + threadIdx.x;
  if (idx >= sch * (CH*H*W)) return;
  int x = idx & 255;
  int y = (idx >> 8) & 255;
  int c = (idx >> 16) & 31;
  int s = idx >> 21;          // CH*H*W == 2^21
  int sg = s0 + s;
  float acc = b1[c];
  #pragma unroll
  for (int ci = 0; ci < CIN; ++ci) {
    const float* zp = z + ((size_t)(sg*CIN + ci) * H) * W;
    const float* wp = w1 + (c*CIN + ci) * 9;
    #pragma unroll
    for (int dy = 0; dy < 3; ++dy) {
      int yy = y + dy - 1;
      if (yy < 0 || yy >= H) continue;
      #pragma unroll
      for (int dx = 0; dx < 3; ++dx) {
        int xx = x + dx - 1;
        if (xx < 0 || xx >= W) continue;
        acc = fmaf(zp[(size_t)yy*W + xx], wp[dy*3+dx], acc);
      }
    }
  }
  x1[idx] = fmaxf(acc, 0.f);
}

// ------------- Kernel 2: conv2 (32->32, 3x3 SAME) + LRN + window -------------
// block = 256 threads = 16x16 spatial tile; each thread owns one pixel, all 32
// output channels in registers (LRN needs the whole channel vector anyway).
__global__ __launch_bounds__(256)
void k_conv2_lrn(const float* __restrict__ x1, const float* __restrict__ w2,
                 const float* __restrict__ b2, const float* __restrict__ cosw,
                 float* __restrict__ x2)
{
  __shared__ float tile[CH*18*18];   // 41472 B: 32 ch x (16+2)^2 halo
  int bw = blockIdx.x, bh = blockIdx.y, s = blockIdx.z;
  int tx = threadIdx.x & 15, ty = threadIdx.x >> 4;
  int w0 = bw*16, h0 = bh*16;
  for (int i = threadIdx.x; i < CH*18*18; i += 256) {
    int ci = i / 324;
    int r  = i - ci*324;
    int iy = r / 18;
    int ix = r - iy*18;
    int gy = h0 + iy - 1, gx = w0 + ix - 1;
    float v = 0.f;
    if (gy >= 0 && gy < H && gx >= 0 && gx < W)
      v = x1[((size_t)(s*CH + ci) * H + gy) * W + gx];
    tile[i] = v;
  }
  __syncthreads();

  float acc[CH];
  #pragma unroll
  for (int co = 0; co < CH; ++co) acc[co] = b2[co];

  for (int ci = 0; ci < CH; ++ci) {
    float tv[9];
    #pragma unroll
    for (int ky = 0; ky < 3; ++ky)
      #pragma unroll
      for (int kx = 0; kx < 3; ++kx)
        tv[ky*3+kx] = tile[ci*324 + (ty+ky)*18 + (tx+kx)];
    #pragma unroll
    for (int co = 0; co < CH; ++co) {
      const float* wp = w2 + (size_t)(co*CH + ci)*9;   // uniform -> scalar loads
      float a = acc[co];
      #pragma unroll
      for (int j = 0; j < 9; ++j) a = fmaf(tv[j], wp[j], a);
      acc[co] = a;
    }
  }

  float sq[CH];
  #pragma unroll
  for (int c = 0; c < CH; ++c) sq[c] = acc[c]*acc[c];

  int y = h0 + ty, x = w0 + tx;
  float cw = cosw[y*W + x];
  #pragma unroll
  for (int c = 0; c < CH; ++c) {
    float win = 0.f;
    #pragma unroll
    for (int d = -2; d <= 2; ++d) {
      int cc = c + d;
      if (cc >= 0 && cc < CH) win += sq[cc];
    }
    float t = fmaf(2e-5f, win, 1.0f);              // 1 + alpha/n * win
    float scale = __powf(t, -0.75f) * cw;          // (..)^-beta * cos_window
    x2[((size_t)(s*CH + c) * H + y) * W + x] = acc[c] * scale;
  }
}

// ---------------- Kernel 3: rfft along W for every row ----------------
// block = 256 thr = 4 waves = 4 rows. Lane j computes bins j and j+64 via the
// (-i)^n factor; bin 128 computed redundantly by all lanes (1 add each).
__global__ __launch_bounds__(256)
void k_rfft_rows(const float* __restrict__ x2, float2* __restrict__ zf)
{
  __shared__ float rows[1024];
  size_t row0 = (size_t)blockIdx.x * 4;
  const float4* src = (const float4*)(x2 + row0 * W);
  ((float4*)rows)[threadIdx.x] = src[threadIdx.x];
  __syncthreads();
  int wv = threadIdx.x >> 6;
  int j  = threadIdx.x & 63;
  const float4* rp = (const float4*)(rows + wv*256);
  float wr = cospif((float)j * (1.f/128.f));
  float wi = -sinpif((float)j * (1.f/128.f));     // e^{-2pi i j/256}
  float cr = 1.f, ci = 0.f;
  float rej=0.f, imj=0.f, re6=0.f, im6=0.f, r128=0.f;
  #pragma unroll 4
  for (int g = 0; g < 64; ++g) {
    float4 v = rp[g];
    // n = 4g+0 : bin64 factor (cr,ci)
    rej = fmaf(v.x, cr, rej);  imj = fmaf(v.x, ci, imj);
    re6 = fmaf(v.x, cr, re6);  im6 = fmaf(v.x, ci, im6);
    r128 += v.x;
    ROT(cr,ci,wr,wi);
    // n = 4g+1 : factor (-i): (ci,-cr)
    rej = fmaf(v.y, cr, rej);  imj = fmaf(v.y, ci, imj);
    re6 = fmaf(v.y, ci, re6);  im6 = fmaf(-v.y, cr, im6);
    r128 -= v.y;
    ROT(cr,ci,wr,wi);
    // n = 4g+2 : factor (-1)
    rej = fmaf(v.z, cr, rej);  imj = fmaf(v.z, ci, imj);
    re6 = fmaf(-v.z, cr, re6); im6 = fmaf(-v.z, ci, im6);
    r128 += v.z;
    ROT(cr,ci,wr,wi);
    // n = 4g+3 : factor (+i): (-ci,cr)
    rej = fmaf(v.w, cr, rej);  imj = fmaf(v.w, ci, imj);
    re6 = fmaf(-v.w, ci, re6); im6 = fmaf(v.w, cr, im6);
    r128 -= v.w;
    ROT(cr,ci,wr,wi);
  }
  float2* op = zf + (row0 + wv) * WF;
  op[j]    = make_float2(rej, imj);
  op[j+64] = make_float2(re6, im6);
  if (j == 0) op[128] = make_float2(r128, 0.f);
}

// ------- Kernel 4: FFT along H + wf elementwise (re/im) + channel sum -------
// one block per (kx, s); thread k owns bins k and k+128 ((-1)^n factor);
// loops c, accumulating g in registers -> ZF2 never materialized.
__global__ __launch_bounds__(128)
void k_colfft_wf(const float2* __restrict__ zf, const float2* __restrict__ wf,
                 float2* __restrict__ G)
{
  __shared__ float2 col[256];
  int kx = blockIdx.x, s = blockIdx.y;
  int k = threadIdx.x;
  float wr = cospif((float)k * (1.f/128.f));
  float wi = -sinpif((float)k * (1.f/128.f));     // forward: e^{-2pi i k/256}
  float g1r=0.f,g1i=0.f,g2r=0.f,g2i=0.f;
  for (int c = 0; c < CH; ++c) {
    __syncthreads();
    const float2* zp = zf + ((size_t)(s*CH + c) * H) * WF + kx;
    col[k]       = zp[(size_t)k * WF];
    col[k + 128] = zp[(size_t)(k+128) * WF];
    __syncthreads();
    float cr=1.f, ci=0.f;
    float z1r=0.f,z1i=0.f,z2r=0.f,z2i=0.f;
    #pragma unroll 4
    for (int n = 0; n < 256; n += 2) {
      float2 a = col[n];
      float ar = a.x*cr - a.y*ci;
      float ai = a.x*ci + a.y*cr;
      z1r += ar; z1i += ai; z2r += ar; z2i += ai;
      ROT(cr,ci,wr,wi);
      float2 b = col[n+1];
      float br = b.x*cr - b.y*ci;
      float bi = b.x*ci + b.y*cr;
      z1r += br; z1i += bi; z2r -= br; z2i -= bi;
      ROT(cr,ci,wr,wi);
    }
    float2 wv1 = wf[((size_t)c * H + k) * WF + kx];
    float2 wv2 = wf[((size_t)c * H + (k+128)) * WF + kx];
    g1r = fmaf( wv1.x, z1r, g1r);     // g_re = wf_re * Re(zf)
    g1i = fmaf(-wv1.y, z1i, g1i);     // g_im = -wf_im * Im(zf)
    g2r = fmaf( wv2.x, z2r, g2r);
    g2i = fmaf(-wv2.y, z2i, g2i);
  }
  float2* gp = G + (size_t)s * H * WF + kx;
  gp[(size_t)k * WF]       = make_float2(g1r, g1i);
  gp[(size_t)(k+128) * WF] = make_float2(g2r, g2i);
}

// ---------------- Kernel 5: inverse complex FFT along H ----------------
__global__ __launch_bounds__(128)
void k_colifft(const float2* __restrict__ G, float2* __restrict__ tmp)
{
  __shared__ float2 col[256];
  int kx = blockIdx.x, s = blockIdx.y;
  int y = threadIdx.x;
  const float2* gp = G + (size_t)s * H * WF + kx;
  col[y]       = gp[(size_t)y * WF];
  col[y + 128] = gp[(size_t)(y+128) * WF];
  __syncthreads();
  float wr = cospif((float)y * (1.f/128.f));
  float wi = sinpif((float)y * (1.f/128.f));      // inverse: e^{+2pi i y/256}
  float cr=1.f, ci=0.f;
  float z1r=0.f,z1i=0.f,z2r=0.f,z2i=0.f;
  #pragma unroll 4
  for (int n = 0; n < 256; n += 2) {
    float2 a = col[n];
    float ar = a.x*cr - a.y*ci;
    float ai = a.x*ci + a.y*cr;
    z1r += ar; z1i += ai; z2r += ar; z2i += ai;
    ROT(cr,ci,wr,wi);
    float2 b = col[n+1];
    float br = b.x*cr - b.y*ci;
    float bi = b.x*ci + b.y*cr;
    z1r += br; z1i += bi; z2r -= br; z2i -= bi;
    ROT(cr,ci,wr,wi);
  }
  float2* tp = tmp + (size_t)s * H * WF + kx;
  tp[(size_t)y * WF]       = make_float2(z1r*(1.f/256.f), z1i*(1.f/256.f));
  tp[(size_t)(y+128) * WF] = make_float2(z2r*(1.f/256.f), z2i*(1.f/256.f));
}

// ---------------- Kernel 6: irfft along W (pocketfft semantics) ----------------
// out[x] = (1/256)[ Re(t0) + (-1)^x Re(t128) + 2*sum_{k=1}^{127} (Re tk cos - Im tk sin) ]
// Im of bins 0 and 128 are IGNORED (numpy irfft behavior).
__global__ __launch_bounds__(256)
void k_irfft_rows(const float2* __restrict__ tmp, float* __restrict__ out,
                  int s0)
{
  __shared__ float2 row[WF];
  int y = blockIdx.x & 255;
  int s = blockIdx.x >> 8;
  const float2* tp = tmp + ((size_t)s * H + y) * WF;
  if (threadIdx.x < WF) row[threadIdx.x] = tp[threadIdx.x];
  __syncthreads();
  int x = threadIdx.x;
  float wr = cospif((float)x * (1.f/128.f));
  float wi = sinpif((float)x * (1.f/128.f));      // e^{+2pi i x/256}
  float cr = 1.f, ci = 0.f;
  float acc = row[0].x + ((x & 1) ? -row[128].x : row[128].x);
  #pragma unroll 4
  for (int k = 1; k <= 127; ++k) {
    ROT(cr,ci,wr,wi);                              // now rot = w^k
    float2 a = row[k];
    acc = fmaf(2.f*a.x, cr, acc);
    acc = fmaf(-2.f*a.y, ci, acc);
  }
  out[((size_t)(s0 + s) * H + y) * W + x] = acc * (1.f/256.f);
}

extern "C" void kernel_launch(void* const* d_in, const int* in_sizes, int n_in,
                              void* d_out, int out_size, void* d_ws, size_t ws_size,
                              hipStream_t stream)
{
  const float*  z    = (const float*)d_in[0];
  const float*  cosw = (const float*)d_in[1];
  const float2* wf   = (const float2*)d_in[2];
  const float*  w1   = (const float*)d_in[3];
  const float*  b1   = (const float*)d_in[4];
  const float*  w2   = (const float*)d_in[5];
  const float*  b2   = (const float*)d_in[6];
  float* out = (float*)d_out;

  // largest per-chunk sample count whose workspace fits
  int sch = 1;
  for (int cand = 64; cand >= 1; cand >>= 1) {
    size_t x1b = (size_t)cand * CH * H * W * 4;        // conv1 out / conv2 out
    size_t zfb = (size_t)cand * CH * H * WF * 8;       // row-fft output
    size_t gb  = (size_t)cand * H * WF * 8;            // G / tmp
    if (2*x1b + zfb + 2*gb <= ws_size) { sch = cand; break; }
  }

  char* p = (char*)d_ws;
  size_t x1b = (size_t)sch * CH * H * W * 4;
  size_t zfb = (size_t)sch * CH * H * WF * 8;
  size_t gb  = (size_t)sch * H * WF * 8;
  float*  X1  = (float*)p;   p += x1b;
  float*  X2  = (float*)p;   p += x1b;
  float2* ZF  = (float2*)p;  p += zfb;
  float2* G   = (float2*)p;  p += gb;
  float2* TMP = (float2*)p;  p += gb;

  for (int s0 = 0; s0 < S_TOT; s0 += sch) {
    k_conv1<<<sch * (CH*H*W) / 256, 256, 0, stream>>>(z, w1, b1, X1, s0, sch);
    k_conv2_lrn<<<dim3(W/16, H/16, sch), 256, 0, stream>>>(X1, w2, b2, cosw, X2);
    k_rfft_rows<<<sch*CH*H/4, 256, 0, stream>>>(X2, ZF);
    k_colfft_wf<<<dim3(WF, sch), 128, 0, stream>>>(ZF, wf, G);
    k_colifft<<<dim3(WF, sch), 128, 0, stream>>>(G, TMP);
    k_irfft_rows<<<sch*H, 256, 0, stream>>>(TMP, out, s0);
  }
}

// Round 9
// 5369.901 us; speedup vs baseline: 1.9036x; 1.9036x over previous
//
#include <hip/hip_runtime.h>
#include <math.h>

#define S_TOT 64
#define CIN   3
#define CH    32
#define H     256
#define W     256
#define WF    129   // W/2+1
#define ZWF   136   // padded row stride for ZF/TMP (1088B = 17*64B aligned)
#define CSPLIT 8    // channel groups for column-forward pass
#define CPG    4    // channels per group (CSPLIT*CPG == CH)

__device__ inline float2 cmulf(float2 a, float2 b) {
  return make_float2(fmaf(a.x, b.x, -(a.y * b.y)), fmaf(a.x, b.y, a.y * b.x));
}

// One radix-4 Stockham stage for a 256-point FFT. j in [0,64). t in [0,4).
// Buffer element n lives at src[n*stride + off]. Forward sign e^{-2pi i/N};
// INV uses conj twiddles and the inverse DFT4.
template<bool INV>
__device__ inline void r4_stage(const float2* __restrict__ src, float2* __restrict__ dst,
                                const float2* __restrict__ tw, int j, int t,
                                int stride, int off)
{
  int Ns   = 1 << (2 * t);                       // 1,4,16,64
  int k    = j & (Ns - 1);
  int base = ((j >> (2 * t)) << (2 * t + 2)) | k; // (j/Ns)*4Ns + k
  int ts   = 64 >> (2 * t);                      // 256/(4Ns)
  float2 a = src[(j      ) * stride + off];
  float2 b = src[(j +  64) * stride + off];
  float2 c = src[(j + 128) * stride + off];
  float2 d = src[(j + 192) * stride + off];
  float2 w1 = tw[k * ts], w2 = tw[2 * k * ts], w3 = tw[3 * k * ts];
  if (INV) { w1.y = -w1.y; w2.y = -w2.y; w3.y = -w3.y; }
  b = cmulf(b, w1); c = cmulf(c, w2); d = cmulf(d, w3);
  float ex = a.x + c.x, ey = a.y + c.y;
  float fx = a.x - c.x, fy = a.y - c.y;
  float gx = b.x + d.x, gy = b.y + d.y;
  float hx = b.x - d.x, hy = b.y - d.y;
  dst[(base         ) * stride + off] = make_float2(ex + gx, ey + gy);
  dst[(base + 2 * Ns) * stride + off] = make_float2(ex - gx, ey - gy);
  if (!INV) {
    dst[(base +     Ns) * stride + off] = make_float2(fx + hy, fy - hx);
    dst[(base + 3 * Ns) * stride + off] = make_float2(fx - hy, fy + hx);
  } else {
    dst[(base +     Ns) * stride + off] = make_float2(fx - hy, fy + hx);
    dst[(base + 3 * Ns) * stride + off] = make_float2(fx + hy, fy - hx);
  }
}

// tw[m] = e^{-2*pi*i*m/256}, m in [0,192)
__device__ inline void build_tw(float2* tw, int tid) {
  if (tid < 192) {
    float fr = (float)tid * (1.0f / 128.0f);
    tw[tid] = make_float2(cospif(fr), -sinpif(fr));
  }
}

// ---------------- Kernel 1: conv1 (3->32, 3x3 SAME) + ReLU ----------------
__global__ __launch_bounds__(256)
void k_conv1(const float* __restrict__ z, const float* __restrict__ w1,
             const float* __restrict__ b1, float* __restrict__ x1, int s0)
{
  int idx = blockIdx.x * 256 + threadIdx.x;
  int x = idx & 255;
  int y = (idx >> 8) & 255;
  int c = (idx >> 16) & 31;
  int s = idx >> 21;          // CH*H*W == 2^21
  int sg = s0 + s;
  float acc = b1[c];
  #pragma unroll
  for (int ci = 0; ci < CIN; ++ci) {
    const float* zp = z + ((size_t)(sg * CIN + ci) * H) * W;
    const float* wp = w1 + (c * CIN + ci) * 9;
    #pragma unroll
    for (int dy = 0; dy < 3; ++dy) {
      int yy = y + dy - 1;
      if (yy < 0 || yy >= H) continue;
      #pragma unroll
      for (int dx = 0; dx < 3; ++dx) {
        int xx = x + dx - 1;
        if (xx < 0 || xx >= W) continue;
        acc = fmaf(zp[(size_t)yy * W + xx], wp[dy * 3 + dx], acc);
      }
    }
  }
  x1[idx] = fmaxf(acc, 0.f);
}

// ------------- Kernel 2: conv2 (32->32, 3x3 SAME) + LRN + window -------------
__global__ __launch_bounds__(256)
void k_conv2_lrn(const float* __restrict__ x1, const float* __restrict__ w2,
                 const float* __restrict__ b2, const float* __restrict__ cosw,
                 float* __restrict__ x2)
{
  __shared__ float tile[CH * 18 * 18];
  int bw = blockIdx.x, bh = blockIdx.y, s = blockIdx.z;
  int tx = threadIdx.x & 15, ty = threadIdx.x >> 4;
  int w0 = bw * 16, h0 = bh * 16;
  for (int i = threadIdx.x; i < CH * 18 * 18; i += 256) {
    int ci = i / 324;
    int r  = i - ci * 324;
    int iy = r / 18;
    int ix = r - iy * 18;
    int gy = h0 + iy - 1, gx = w0 + ix - 1;
    float v = 0.f;
    if (gy >= 0 && gy < H && gx >= 0 && gx < W)
      v = x1[((size_t)(s * CH + ci) * H + gy) * W + gx];
    tile[i] = v;
  }
  __syncthreads();

  float acc[CH];
  #pragma unroll
  for (int co = 0; co < CH; ++co) acc[co] = b2[co];

  for (int ci = 0; ci < CH; ++ci) {
    float tv[9];
    #pragma unroll
    for (int ky = 0; ky < 3; ++ky)
      #pragma unroll
      for (int kx = 0; kx < 3; ++kx)
        tv[ky * 3 + kx] = tile[ci * 324 + (ty + ky) * 18 + (tx + kx)];
    #pragma unroll
    for (int co = 0; co < CH; ++co) {
      const float* wp = w2 + (size_t)(co * CH + ci) * 9;
      float a = acc[co];
      #pragma unroll
      for (int j = 0; j < 9; ++j) a = fmaf(tv[j], wp[j], a);
      acc[co] = a;
    }
  }

  float sq[CH];
  #pragma unroll
  for (int c = 0; c < CH; ++c) sq[c] = acc[c] * acc[c];

  int y = h0 + ty, x = w0 + tx;
  float cw = cosw[y * W + x];
  #pragma unroll
  for (int c = 0; c < CH; ++c) {
    float win = 0.f;
    #pragma unroll
    for (int d = -2; d <= 2; ++d) {
      int cc = c + d;
      if (cc >= 0 && cc < CH) win += sq[cc];
    }
    float t = fmaf(2e-5f, win, 1.0f);
    float scale = __powf(t, -0.75f) * cw;
    x2[((size_t)(s * CH + c) * H + y) * W + x] = acc[c] * scale;
  }
}

// ---------- Kernel 3: row rfft, 2 real rows packed per complex FFT ----------
// block = 256 = 4 waves; one 256-pt radix-4 Stockham FFT per wave (j = lane).
__global__ __launch_bounds__(256)
void k_rfft_rows(const float* __restrict__ x2, float2* __restrict__ zf)
{
  __shared__ float2 bufA[4 * 256], bufB[4 * 256], tw[192];
  int tid = threadIdx.x;
  build_tw(tw, tid);
  int w = tid >> 6, j = tid & 63;
  int fid = blockIdx.x * 4 + w;
  size_t rowA = (size_t)fid * 2, rowB = rowA + 1;
  float2* A = bufA + w * 256;
  float2* B = bufB + w * 256;
  const float* pa = x2 + rowA * W;
  const float* pb = x2 + rowB * W;
  #pragma unroll
  for (int q = 0; q < 4; ++q) { int n = j + 64 * q; A[n] = make_float2(pa[n], pb[n]); }
  __syncthreads();
  #pragma unroll
  for (int t = 0; t < 4; ++t) {
    const float2* src = (t & 1) ? B : A;
    float2*       dst = (t & 1) ? A : B;
    r4_stage<false>(src, dst, tw, j, t, 1, 0);
    __syncthreads();
  }
  // result in A (natural order). Untangle: A=even-packed real row, B=odd.
  float2* op_a = zf + rowA * ZWF;
  float2* op_b = zf + rowB * ZWF;
  {
    int k = j, m = (256 - j) & 255;
    float2 zk = A[k], zm = A[m];
    op_a[k] = make_float2(0.5f * (zk.x + zm.x),  0.5f * (zk.y - zm.y));
    op_b[k] = make_float2(0.5f * (zk.y + zm.y), -0.5f * (zk.x - zm.x));
  }
  {
    int k = j + 64, m = 192 - j;
    float2 zk = A[k], zm = A[m];
    op_a[k] = make_float2(0.5f * (zk.x + zm.x),  0.5f * (zk.y - zm.y));
    op_b[k] = make_float2(0.5f * (zk.y + zm.y), -0.5f * (zk.x - zm.x));
  }
  if (j == 0) {
    float2 z128 = A[128];
    op_a[128] = make_float2(z128.x, 0.f);
    op_b[128] = make_float2(z128.y, 0.f);
  }
}

// ------ Kernel 4: forward column FFT (axis H) x wf + partial channel sum ------
// grid (17 tiles of 8 kx, sch, CSPLIT). Tile of 8 columns x 256 rows in LDS
// (stride 9 pad). Per channel: load -> 4-stage FFT -> multiply wf, accumulate
// G partial in registers. Writes gpart[part].
__global__ __launch_bounds__(256)
void k_colfwd(const float2* __restrict__ zf, const float2* __restrict__ wf,
              float2* __restrict__ gpart, int sch)
{
  __shared__ float2 A[256 * 9], B[256 * 9], tw[192];
  int tid = threadIdx.x;
  build_tw(tw, tid);
  int tile = blockIdx.x, s = blockIdx.y, part = blockIdx.z;
  int col = tid & 7, jb = tid >> 3;           // jb in [0,32)
  int kx = tile * 8 + col;
  bool kv = (kx < WF);
  float2 gacc[8];
  #pragma unroll
  for (int i = 0; i < 8; ++i) gacc[i] = make_float2(0.f, 0.f);

  for (int cc = 0; cc < CPG; ++cc) {
    int c = part * CPG + cc;
    const float2* zp = zf + ((size_t)(s * CH + c) * H) * ZWF;
    __syncthreads();                          // A readers from prev iter done
    #pragma unroll
    for (int i = 0; i < 8; ++i) {
      int n = jb + 32 * i;
      float2 v = kv ? zp[(size_t)n * ZWF + kx] : make_float2(0.f, 0.f);
      A[n * 9 + col] = v;
    }
    __syncthreads();
    #pragma unroll
    for (int t = 0; t < 4; ++t) {
      const float2* src = (t & 1) ? B : A;
      float2*       dst = (t & 1) ? A : B;
      r4_stage<false>(src, dst, tw, jb,      t, 9, col);
      r4_stage<false>(src, dst, tw, jb + 32, t, 9, col);
      __syncthreads();
    }
    // result in A
    const float2* wp = wf + (size_t)c * H * WF;
    #pragma unroll
    for (int i = 0; i < 8; ++i) {
      int n = jb + 32 * i;
      float2 zv = A[n * 9 + col];
      float2 wv = kv ? wp[(size_t)n * WF + kx] : make_float2(0.f, 0.f);
      gacc[i].x = fmaf( wv.x, zv.x, gacc[i].x);   // g_re += wf_re * Re
      gacc[i].y = fmaf(-wv.y, zv.y, gacc[i].y);   // g_im -= wf_im * Im
    }
  }
  if (kv) {
    float2* gp = gpart + ((size_t)(part * sch + s) * H) * ZWF;
    #pragma unroll
    for (int i = 0; i < 8; ++i) { int n = jb + 32 * i; gp[(size_t)n * ZWF + kx] = gacc[i]; }
  }
}

// ------ Kernel 5: sum partials + inverse column FFT (axis H) -> TMP ------
__global__ __launch_bounds__(256)
void k_colinv(const float2* __restrict__ gpart, float2* __restrict__ tmp, int sch)
{
  __shared__ float2 A[256 * 9], B[256 * 9], tw[192];
  int tid = threadIdx.x;
  build_tw(tw, tid);
  int tile = blockIdx.x, s = blockIdx.y;
  int col = tid & 7, jb = tid >> 3;
  int kx = tile * 8 + col;
  bool kv = (kx < WF);
  #pragma unroll
  for (int i = 0; i < 8; ++i) {
    int n = jb + 32 * i;
    float2 acc = make_float2(0.f, 0.f);
    if (kv) {
      #pragma unroll
      for (int p = 0; p < CSPLIT; ++p) {
        float2 v = gpart[((size_t)(p * sch + s) * H + n) * ZWF + kx];
        acc.x += v.x; acc.y += v.y;
      }
    }
    A[n * 9 + col] = acc;
  }
  __syncthreads();
  #pragma unroll
  for (int t = 0; t < 4; ++t) {
    const float2* src = (t & 1) ? B : A;
    float2*       dst = (t & 1) ? A : B;
    r4_stage<true>(src, dst, tw, jb,      t, 9, col);
    r4_stage<true>(src, dst, tw, jb + 32, t, 9, col);
    __syncthreads();
  }
  if (kv) {
    float2* tp = tmp + (size_t)s * H * ZWF;
    #pragma unroll
    for (int i = 0; i < 8; ++i) { int n = jb + 32 * i; tp[(size_t)n * ZWF + kx] = A[n * 9 + col]; }
  }
}

// ------ Kernel 6: row irfft, 2 output rows packed per inverse complex FFT ------
// numpy irfft semantics: Im of bins 0 and 128 ignored. Scale 1/65536 (both axes).
__global__ __launch_bounds__(256)
void k_irfft_rows(const float2* __restrict__ tmp, float* __restrict__ out, int s0)
{
  __shared__ float2 bufA[4 * 256], bufB[4 * 256], tw[192];
  int tid = threadIdx.x;
  build_tw(tw, tid);
  int w = tid >> 6, j = tid & 63;
  int fid = blockIdx.x * 4 + w;
  int s = fid >> 7, q = fid & 127;
  int hA = 2 * q, hB = hA + 1;
  const float2* ta = tmp + ((size_t)s * H + hA) * ZWF;
  const float2* tb = tmp + ((size_t)s * H + hB) * ZWF;
  float2* A = bufA + w * 256;
  float2* B = bufB + w * 256;
  // Z[n] = ZA[n] + i*ZB[n], ZA/ZB Hermitian-extended spectra (Im@0,128 -> 0)
  {
    float2 a0 = ta[j], b0 = tb[j];                 // n = j
    if (j == 0) { a0.y = 0.f; b0.y = 0.f; }
    A[j] = make_float2(a0.x - b0.y, a0.y + b0.x);
    float2 a1 = ta[j + 64], b1 = tb[j + 64];       // n = j+64
    A[j + 64] = make_float2(a1.x - b1.y, a1.y + b1.x);
    float2 a2 = ta[128 - j], b2 = tb[128 - j];     // n = j+128 -> conj T[128-j]
    if (j == 0) { a2.y = 0.f; b2.y = 0.f; }
    a2.y = -a2.y; b2.y = -b2.y;
    A[j + 128] = make_float2(a2.x - b2.y, a2.y + b2.x);
    float2 a3 = ta[64 - j], b3 = tb[64 - j];       // n = j+192 -> conj T[64-j]
    a3.y = -a3.y; b3.y = -b3.y;
    A[j + 192] = make_float2(a3.x - b3.y, a3.y + b3.x);
  }
  __syncthreads();
  #pragma unroll
  for (int t = 0; t < 4; ++t) {
    const float2* src = (t & 1) ? B : A;
    float2*       dst = (t & 1) ? A : B;
    r4_stage<true>(src, dst, tw, j, t, 1, 0);
    __syncthreads();
  }
  const float sc = 1.0f / 65536.0f;
  float* oa = out + ((size_t)(s0 + s) * H + hA) * W;
  float* ob = out + ((size_t)(s0 + s) * H + hB) * W;
  #pragma unroll
  for (int q4 = 0; q4 < 4; ++q4) {
    int n = j + 64 * q4;
    float2 zv = A[n];
    oa[n] = zv.x * sc;
    ob[n] = zv.y * sc;
  }
}

extern "C" void kernel_launch(void* const* d_in, const int* in_sizes, int n_in,
                              void* d_out, int out_size, void* d_ws, size_t ws_size,
                              hipStream_t stream)
{
  const float*  z    = (const float*)d_in[0];
  const float*  cosw = (const float*)d_in[1];
  const float2* wf   = (const float2*)d_in[2];
  const float*  w1   = (const float*)d_in[3];
  const float*  b1   = (const float*)d_in[4];
  const float*  w2   = (const float*)d_in[5];
  const float*  b2   = (const float*)d_in[6];
  float* out = (float*)d_out;

  // per-sample workspace bytes
  size_t x1b = (size_t)CH * H * W * 4;              // conv1 out
  size_t x2b = x1b;                                 // conv2 out
  size_t zfb = (size_t)CH * H * ZWF * 8;            // row-fft out (padded)
  size_t gpb = (size_t)CSPLIT * H * ZWF * 8;        // partial G
  size_t tpb = (size_t)H * ZWF * 8;                 // after inverse col fft
  size_t per = x1b + x2b + zfb + gpb + tpb;

  int sch = (int)(ws_size / per);
  if (sch > S_TOT) sch = S_TOT;
  if (sch < 1) sch = 1;

  char* p = (char*)d_ws;
  float*  X1  = (float*)p;   p += x1b * sch;
  float*  X2  = (float*)p;   p += x2b * sch;
  float2* ZF  = (float2*)p;  p += zfb * sch;
  float2* GP  = (float2*)p;  p += gpb * sch;
  float2* TMP = (float2*)p;  p += tpb * sch;

  for (int s0 = 0; s0 < S_TOT; s0 += sch) {
    int cur = S_TOT - s0; if (cur > sch) cur = sch;
    k_conv1<<<cur * 8192, 256, 0, stream>>>(z, w1, b1, X1, s0);
    k_conv2_lrn<<<dim3(16, 16, cur), 256, 0, stream>>>(X1, w2, b2, cosw, X2);
    k_rfft_rows<<<cur * 1024, 256, 0, stream>>>(X2, ZF);
    k_colfwd<<<dim3(17, cur, CSPLIT), 256, 0, stream>>>(ZF, wf, GP, sch);
    k_colinv<<<dim3(17, cur), 256, 0, stream>>>(GP, TMP, sch);
    k_irfft_rows<<<cur * 32, 256, 0, stream>>>(TMP, out, s0);
  }
}

// Round 11
// 1868.265 us; speedup vs baseline: 5.4715x; 2.8743x over previous
//
#include <hip/hip_runtime.h>
#include <math.h>

#define S_TOT 64
#define CIN   3
#define CH    32
#define H     256
#define W     256
#define WF    129   // W/2+1
#define ZWF   136   // padded row stride for ZF/TMP (1088B = 17*64B aligned)
#define CSPLIT 8    // channel groups for column-forward pass
#define CPG    4    // channels per group (CSPLIT*CPG == CH)

typedef unsigned short u16;
typedef unsigned int   u32;
using bf16x8 = __attribute__((ext_vector_type(8))) short;
using f32x4  = __attribute__((ext_vector_type(4))) float;

__device__ inline float2 cmulf(float2 a, float2 b) {
  return make_float2(fmaf(a.x, b.x, -(a.y * b.y)), fmaf(a.x, b.y, a.y * b.x));
}

// round-to-nearest-even fp32 -> bf16
__device__ inline u16 rne_bf16(float f) {
  u32 u = __float_as_uint(f);
  u32 r = (u + 0x7FFFu + ((u >> 16) & 1u)) >> 16;
  return (u16)r;
}

// LDS XOR swizzle: relocate 16B blocks within 128B window by 64B-chunk index.
// Bijective; apply on BOTH write and read byte offsets. Keeps 16B alignment.
__device__ inline u32 swz(u32 a) { return a ^ (((a >> 6) & 7u) << 4); }

// ---------------- radix-4 Stockham FFT machinery (unchanged) ----------------
template<bool INV>
__device__ inline void r4_stage(const float2* __restrict__ src, float2* __restrict__ dst,
                                const float2* __restrict__ tw, int j, int t,
                                int stride, int off)
{
  int Ns   = 1 << (2 * t);
  int k    = j & (Ns - 1);
  int base = ((j >> (2 * t)) << (2 * t + 2)) | k;
  int ts   = 64 >> (2 * t);
  float2 a = src[(j      ) * stride + off];
  float2 b = src[(j +  64) * stride + off];
  float2 c = src[(j + 128) * stride + off];
  float2 d = src[(j + 192) * stride + off];
  float2 w1 = tw[k * ts], w2 = tw[2 * k * ts], w3 = tw[3 * k * ts];
  if (INV) { w1.y = -w1.y; w2.y = -w2.y; w3.y = -w3.y; }
  b = cmulf(b, w1); c = cmulf(c, w2); d = cmulf(d, w3);
  float ex = a.x + c.x, ey = a.y + c.y;
  float fx = a.x - c.x, fy = a.y - c.y;
  float gx = b.x + d.x, gy = b.y + d.y;
  float hx = b.x - d.x, hy = b.y - d.y;
  dst[(base         ) * stride + off] = make_float2(ex + gx, ey + gy);
  dst[(base + 2 * Ns) * stride + off] = make_float2(ex - gx, ey - gy);
  if (!INV) {
    dst[(base +     Ns) * stride + off] = make_float2(fx + hy, fy - hx);
    dst[(base + 3 * Ns) * stride + off] = make_float2(fx - hy, fy + hx);
  } else {
    dst[(base +     Ns) * stride + off] = make_float2(fx - hy, fy + hx);
    dst[(base + 3 * Ns) * stride + off] = make_float2(fx + hy, fy - hx);
  }
}

__device__ inline void build_tw(float2* tw, int tid) {
  if (tid < 192) {
    float fr = (float)tid * (1.0f / 128.0f);
    tw[tid] = make_float2(cospif(fr), -sinpif(fr));
  }
}

// ------ Kernel 1: conv1 (3->32, 3x3 SAME) + ReLU -> NHWC bf16 ------
// thread = (co = tid&31, x-slot = tid>>5). Block covers 8 x-cols x 16 rows.
// Weights per-lane in 27 VGPRs (lane owns co) -> no uniform-operand streaming.
// Sliding 3-row window of z in registers: 9 loads + 27 FMA per output row.
__global__ __launch_bounds__(256)
void k_conv1(const float* __restrict__ z, const float* __restrict__ w1,
             const float* __restrict__ b1, u16* __restrict__ x1h, int s0)
{
  int tid = threadIdx.x;
  int co = tid & 31, xs = tid >> 5;
  int x  = blockIdx.x * 8 + xs;
  int y0 = blockIdx.y * 16;
  int s  = blockIdx.z;

  float wr[27];
  #pragma unroll
  for (int i = 0; i < 27; ++i) {
    int ci = i / 9, t = i - ci * 9;
    wr[i] = w1[(co * CIN + ci) * 9 + t];
  }
  float bias = b1[co];
  const float* zs = z + (size_t)(s0 + s) * CIN * H * W;

  float rb[3][9];   // [row slot][ci*3 + col]
  // preload rows y0-1 (slot 0) and y0 (slot 1)
  #pragma unroll
  for (int pre = 0; pre < 2; ++pre) {
    int yy = y0 - 1 + pre;
    #pragma unroll
    for (int ci = 0; ci < 3; ++ci)
      #pragma unroll
      for (int c = 0; c < 3; ++c) {
        int xx = x - 1 + c;
        float v = 0.f;
        if (yy >= 0 && yy < H && xx >= 0 && xx < W) v = zs[ci * (H*W) + yy * W + xx];
        rb[pre][ci * 3 + c] = v;
      }
  }
  u16* op = x1h + ((size_t)s * H * W) * CH;
  #pragma unroll
  for (int r = 0; r < 16; ++r) {
    int yy = y0 + r + 1;                 // new bottom row -> slot (r+2)%3
    int sl2 = (r + 2) % 3;
    #pragma unroll
    for (int ci = 0; ci < 3; ++ci)
      #pragma unroll
      for (int c = 0; c < 3; ++c) {
        int xx = x - 1 + c;
        float v = 0.f;
        if (yy >= 0 && yy < H && xx >= 0 && xx < W) v = zs[ci * (H*W) + yy * W + xx];
        rb[sl2][ci * 3 + c] = v;
      }
    float acc = bias;
    #pragma unroll
    for (int ci = 0; ci < 3; ++ci)
      #pragma unroll
      for (int ky = 0; ky < 3; ++ky) {
        int sl = (r + ky) % 3;
        #pragma unroll
        for (int kx = 0; kx < 3; ++kx)
          acc = fmaf(rb[sl][ci * 3 + kx], wr[ci * 9 + ky * 3 + kx], acc);
      }
    acc = fmaxf(acc, 0.f);
    op[((size_t)(y0 + r) * W + x) * CH + co] = rne_bf16(acc);
  }
}

// ------ Kernel 2: conv2 via bf16 MFMA (K=ci per tap) + LRN + window ------
// Block = 256 thr = 4 waves; tile 8 rows x 16 cols x 32 co.
// A[px][ci] = x1h slice (shifted per tap), B[ci][co] = w2 tap slice.
// 9 taps x 1 MFMA accumulate -> full K=288 conv. fp32 accumulation.
__global__ __launch_bounds__(256)
void k_conv2_mfma(const u16* __restrict__ x1h, const float* __restrict__ w2,
                  const float* __restrict__ b2, const float* __restrict__ cosw,
                  float* __restrict__ x2)
{
  __shared__ u16  tileh[10 * 18 * 32];   // [row][col][ci], swizzled, 11.5 KB
  __shared__ u16  wlds[9 * 32 * 32];     // [tap][co][ci], swizzled, 18.4 KB
  __shared__ float xc[8 * 16 * 33];      // [row][px][co+pad] epilogue, 16.9 KB

  int tid = threadIdx.x;
  int x0 = blockIdx.x * 16;
  int y0 = blockIdx.y * 8;
  int s  = blockIdx.z;
  char* tb = (char*)tileh;
  char* wb = (char*)wlds;

  // stage weights: wlds[t][co][ci] = bf16(w2[co][ci][t])
  for (int i = tid; i < 9 * 32 * 32; i += 256) {
    int t = i >> 10, rem = i & 1023, co = rem >> 5, ci = rem & 31;
    u16 v = rne_bf16(w2[((size_t)co * CH + ci) * 9 + t]);
    *(u16*)(wb + swz((u32)i * 2)) = v;
  }
  // stage x1h tile rows y0-1..y0+8, cols x0-1..x0+16 (zero halo), uint granularity
  const u16* xp = x1h + ((size_t)s * H * W) * CH;
  for (int i = tid; i < 10 * 18 * 16; i += 256) {
    int q = i & 15, rc = i >> 4;
    int col = rc % 18, row = rc / 18;
    int y = y0 - 1 + row, xg = x0 - 1 + col;
    u32 v = 0;
    if (y >= 0 && y < H && xg >= 0 && xg < W)
      v = *(const u32*)(xp + ((size_t)y * W + xg) * CH + q * 2);
    *(u32*)(tb + swz(((u32)(row * 18 + col) * 32 + (u32)q * 2) * 2)) = v;
  }
  __syncthreads();

  int wv = tid >> 6, l = tid & 63;
  int lm = l & 15, lg = l >> 4;
  int r0 = 2 * wv, r1 = 2 * wv + 1;      // pixel rows of this wave

  f32x4 acc[2][2];
  {
    float bv0 = b2[lm], bv1 = b2[16 + lm];
    acc[0][0] = f32x4{bv0, bv0, bv0, bv0};
    acc[0][1] = f32x4{bv1, bv1, bv1, bv1};
    acc[1][0] = acc[0][0];
    acc[1][1] = acc[0][1];
  }
  #pragma unroll
  for (int ky = 0; ky < 3; ++ky) {
    #pragma unroll
    for (int kx = 0; kx < 3; ++kx) {
      int t = ky * 3 + kx;
      bf16x8 bf0 = *(bf16x8*)(wb + swz((((u32)t * 32 +      lm) * 32 + (u32)lg * 8) * 2));
      bf16x8 bf1 = *(bf16x8*)(wb + swz((((u32)t * 32 + 16 + lm) * 32 + (u32)lg * 8) * 2));
      bf16x8 a0  = *(bf16x8*)(tb + swz((((u32)(r0 + ky) * 18 + lm + kx) * 32 + (u32)lg * 8) * 2));
      bf16x8 a1  = *(bf16x8*)(tb + swz((((u32)(r1 + ky) * 18 + lm + kx) * 32 + (u32)lg * 8) * 2));
      acc[0][0] = __builtin_amdgcn_mfma_f32_16x16x32_bf16(a0, bf0, acc[0][0], 0, 0, 0);
      acc[0][1] = __builtin_amdgcn_mfma_f32_16x16x32_bf16(a0, bf1, acc[0][1], 0, 0, 0);
      acc[1][0] = __builtin_amdgcn_mfma_f32_16x16x32_bf16(a1, bf0, acc[1][0], 0, 0, 0);
      acc[1][1] = __builtin_amdgcn_mfma_f32_16x16x32_bf16(a1, bf1, acc[1][1], 0, 0, 0);
    }
  }
  // C layout: col(N=co) = lane&15, row(M=px) = (lane>>4)*4 + reg
  #pragma unroll
  for (int r = 0; r < 2; ++r)
    #pragma unroll
    for (int n = 0; n < 2; ++n)
      #pragma unroll
      for (int e = 0; e < 4; ++e) {
        int px = lg * 4 + e, co = n * 16 + lm, row = 2 * wv + r;
        xc[((row * 16 + px) * 33) + co] = acc[r][n][e];
      }
  __syncthreads();

  // LRN + cosine window + store planar fp32 X2[s][co][y][x]
  int xq = tid & 15, set = tid >> 4;
  #pragma unroll
  for (int j = 0; j < 16; ++j) {
    int combo = set * 16 + j;
    int row = combo >> 5, co = combo & 31;
    float v = xc[((row * 16 + xq) * 33) + co];
    float win = v * v;
    #pragma unroll
    for (int d = 1; d <= 2; ++d) {
      if (co - d >= 0)  { float u = xc[((row * 16 + xq) * 33) + co - d]; win = fmaf(u, u, win); }
      if (co + d < 32)  { float u = xc[((row * 16 + xq) * 33) + co + d]; win = fmaf(u, u, win); }
    }
    int y = y0 + row, xg = x0 + xq;
    float t = fmaf(2e-5f, win, 1.0f);
    float scale = __powf(t, -0.75f) * cosw[y * W + xg];
    x2[((size_t)(s * CH + co) * H + y) * W + xg] = v * scale;
  }
}

// ---------- Kernel 3: row rfft, 2 real rows packed per complex FFT ----------
__global__ __launch_bounds__(256)
void k_rfft_rows(const float* __restrict__ x2, float2* __restrict__ zf)
{
  __shared__ float2 bufA[4 * 256], bufB[4 * 256], tw[192];
  int tid = threadIdx.x;
  build_tw(tw, tid);
  int w = tid >> 6, j = tid & 63;
  int fid = blockIdx.x * 4 + w;
  size_t rowA = (size_t)fid * 2, rowB = rowA + 1;
  float2* A = bufA + w * 256;
  float2* B = bufB + w * 256;
  const float* pa = x2 + rowA * W;
  const float* pb = x2 + rowB * W;
  #pragma unroll
  for (int q = 0; q < 4; ++q) { int n = j + 64 * q; A[n] = make_float2(pa[n], pb[n]); }
  __syncthreads();
  #pragma unroll
  for (int t = 0; t < 4; ++t) {
    const float2* src = (t & 1) ? B : A;
    float2*       dst = (t & 1) ? A : B;
    r4_stage<false>(src, dst, tw, j, t, 1, 0);
    __syncthreads();
  }
  float2* op_a = zf + rowA * ZWF;
  float2* op_b = zf + rowB * ZWF;
  {
    int k = j, m = (256 - j) & 255;
    float2 zk = A[k], zm = A[m];
    op_a[k] = make_float2(0.5f * (zk.x + zm.x),  0.5f * (zk.y - zm.y));
    op_b[k] = make_float2(0.5f * (zk.y + zm.y), -0.5f * (zk.x - zm.x));
  }
  {
    int k = j + 64, m = 192 - j;
    float2 zk = A[k], zm = A[m];
    op_a[k] = make_float2(0.5f * (zk.x + zm.x),  0.5f * (zk.y - zm.y));
    op_b[k] = make_float2(0.5f * (zk.y + zm.y), -0.5f * (zk.x - zm.x));
  }
  if (j == 0) {
    float2 z128 = A[128];
    op_a[128] = make_float2(z128.x, 0.f);
    op_b[128] = make_float2(z128.y, 0.f);
  }
}

// ------ Kernel 4: forward column FFT (axis H) x wf + partial channel sum ------
__global__ __launch_bounds__(256)
void k_colfwd(const float2* __restrict__ zf, const float2* __restrict__ wf,
              float2* __restrict__ gpart, int sch)
{
  __shared__ float2 A[256 * 9], B[256 * 9], tw[192];
  int tid = threadIdx.x;
  build_tw(tw, tid);
  int tile = blockIdx.x, s = blockIdx.y, part = blockIdx.z;
  int col = tid & 7, jb = tid >> 3;
  int kx = tile * 8 + col;
  bool kv = (kx < WF);
  float2 gacc[8];
  #pragma unroll
  for (int i = 0; i < 8; ++i) gacc[i] = make_float2(0.f, 0.f);

  for (int cc = 0; cc < CPG; ++cc) {
    int c = part * CPG + cc;
    const float2* zp = zf + ((size_t)(s * CH + c) * H) * ZWF;
    __syncthreads();
    #pragma unroll
    for (int i = 0; i < 8; ++i) {
      int n = jb + 32 * i;
      float2 v = kv ? zp[(size_t)n * ZWF + kx] : make_float2(0.f, 0.f);
      A[n * 9 + col] = v;
    }
    __syncthreads();
    #pragma unroll
    for (int t = 0; t < 4; ++t) {
      const float2* src = (t & 1) ? B : A;
      float2*       dst = (t & 1) ? A : B;
      r4_stage<false>(src, dst, tw, jb,      t, 9, col);
      r4_stage<false>(src, dst, tw, jb + 32, t, 9, col);
      __syncthreads();
    }
    const float2* wp = wf + (size_t)c * H * WF;
    #pragma unroll
    for (int i = 0; i < 8; ++i) {
      int n = jb + 32 * i;
      float2 zv = A[n * 9 + col];
      float2 wv = kv ? wp[(size_t)n * WF + kx] : make_float2(0.f, 0.f);
      gacc[i].x = fmaf( wv.x, zv.x, gacc[i].x);
      gacc[i].y = fmaf(-wv.y, zv.y, gacc[i].y);
    }
  }
  if (kv) {
    float2* gp = gpart + ((size_t)(part * sch + s) * H) * ZWF;
    #pragma unroll
    for (int i = 0; i < 8; ++i) { int n = jb + 32 * i; gp[(size_t)n * ZWF + kx] = gacc[i]; }
  }
}

// ------ Kernel 5: sum partials + inverse column FFT (axis H) -> TMP ------
__global__ __launch_bounds__(256)
void k_colinv(const float2* __restrict__ gpart, float2* __restrict__ tmp, int sch)
{
  __shared__ float2 A[256 * 9], B[256 * 9], tw[192];
  int tid = threadIdx.x;
  build_tw(tw, tid);
  int tile = blockIdx.x, s = blockIdx.y;
  int col = tid & 7, jb = tid >> 3;
  int kx = tile * 8 + col;
  bool kv = (kx < WF);
  #pragma unroll
  for (int i = 0; i < 8; ++i) {
    int n = jb + 32 * i;
    float2 acc = make_float2(0.f, 0.f);
    if (kv) {
      #pragma unroll
      for (int p = 0; p < CSPLIT; ++p) {
        float2 v = gpart[((size_t)(p * sch + s) * H + n) * ZWF + kx];
        acc.x += v.x; acc.y += v.y;
      }
    }
    A[n * 9 + col] = acc;
  }
  __syncthreads();
  #pragma unroll
  for (int t = 0; t < 4; ++t) {
    const float2* src = (t & 1) ? B : A;
    float2*       dst = (t & 1) ? A : B;
    r4_stage<true>(src, dst, tw, jb,      t, 9, col);
    r4_stage<true>(src, dst, tw, jb + 32, t, 9, col);
    __syncthreads();
  }
  if (kv) {
    float2* tp = tmp + (size_t)s * H * ZWF;
    #pragma unroll
    for (int i = 0; i < 8; ++i) { int n = jb + 32 * i; tp[(size_t)n * ZWF + kx] = A[n * 9 + col]; }
  }
}

// ------ Kernel 6: row irfft, 2 output rows packed per inverse complex FFT ------
__global__ __launch_bounds__(256)
void k_irfft_rows(const float2* __restrict__ tmp, float* __restrict__ out, int s0)
{
  __shared__ float2 bufA[4 * 256], bufB[4 * 256], tw[192];
  int tid = threadIdx.x;
  build_tw(tw, tid);
  int w = tid >> 6, j = tid & 63;
  int fid = blockIdx.x * 4 + w;
  int s = fid >> 7, q = fid & 127;
  int hA = 2 * q, hB = hA + 1;
  const float2* ta = tmp + ((size_t)s * H + hA) * ZWF;
  const float2* tb = tmp + ((size_t)s * H + hB) * ZWF;
  float2* A = bufA + w * 256;
  float2* B = bufB + w * 256;
  {
    float2 a0 = ta[j], b0 = tb[j];
    if (j == 0) { a0.y = 0.f; b0.y = 0.f; }
    A[j] = make_float2(a0.x - b0.y, a0.y + b0.x);
    float2 a1 = ta[j + 64], b1 = tb[j + 64];
    A[j + 64] = make_float2(a1.x - b1.y, a1.y + b1.x);
    float2 a2 = ta[128 - j], b2 = tb[128 - j];
    if (j == 0) { a2.y = 0.f; b2.y = 0.f; }
    a2.y = -a2.y; b2.y = -b2.y;
    A[j + 128] = make_float2(a2.x - b2.y, a2.y + b2.x);
    float2 a3 = ta[64 - j], b3 = tb[64 - j];
    a3.y = -a3.y; b3.y = -b3.y;
    A[j + 192] = make_float2(a3.x - b3.y, a3.y + b3.x);
  }
  __syncthreads();
  #pragma unroll
  for (int t = 0; t < 4; ++t) {
    const float2* src = (t & 1) ? B : A;
    float2*       dst = (t & 1) ? A : B;
    r4_stage<true>(src, dst, tw, j, t, 1, 0);
    __syncthreads();
  }
  const float sc = 1.0f / 65536.0f;
  float* oa = out + ((size_t)(s0 + s) * H + hA) * W;
  float* ob = out + ((size_t)(s0 + s) * H + hB) * W;
  #pragma unroll
  for (int q4 = 0; q4 < 4; ++q4) {
    int n = j + 64 * q4;
    float2 zv = A[n];
    oa[n] = zv.x * sc;
    ob[n] = zv.y * sc;
  }
}

extern "C" void kernel_launch(void* const* d_in, const int* in_sizes, int n_in,
                              void* d_out, int out_size, void* d_ws, size_t ws_size,
                              hipStream_t stream)
{
  const float*  z    = (const float*)d_in[0];
  const float*  cosw = (const float*)d_in[1];
  const float2* wf   = (const float2*)d_in[2];
  const float*  w1   = (const float*)d_in[3];
  const float*  b1   = (const float*)d_in[4];
  const float*  w2   = (const float*)d_in[5];
  const float*  b2   = (const float*)d_in[6];
  float* out = (float*)d_out;

  // per-sample workspace bytes
  size_t x1hb = (size_t)H * W * CH * 2;             // conv1 out, NHWC bf16
  size_t x2b  = (size_t)CH * H * W * 4;             // conv2 out, planar fp32
  size_t zfb  = (size_t)CH * H * ZWF * 8;           // row-fft out (padded)
  size_t gpb  = (size_t)CSPLIT * H * ZWF * 8;       // partial G
  size_t tpb  = (size_t)H * ZWF * 8;                // after inverse col fft
  size_t per  = x1hb + x2b + zfb + gpb + tpb;

  int sch = (int)(ws_size / per);
  if (sch > S_TOT) sch = S_TOT;
  if (sch < 1) sch = 1;

  char* p = (char*)d_ws;
  u16*    X1H = (u16*)p;    p += x1hb * sch;
  float*  X2  = (float*)p;  p += x2b * sch;
  float2* ZF  = (float2*)p; p += zfb * sch;
  float2* GP  = (float2*)p; p += gpb * sch;
  float2* TMP = (float2*)p; p += tpb * sch;

  for (int s0 = 0; s0 < S_TOT; s0 += sch) {
    int cur = S_TOT - s0; if (cur > sch) cur = sch;
    k_conv1<<<dim3(W/8, H/16, cur), 256, 0, stream>>>(z, w1, b1, X1H, s0);
    k_conv2_mfma<<<dim3(W/16, H/8, cur), 256, 0, stream>>>(X1H, w2, b2, cosw, X2);
    k_rfft_rows<<<cur * 1024, 256, 0, stream>>>(X2, ZF);
    k_colfwd<<<dim3(17, cur, CSPLIT), 256, 0, stream>>>(ZF, wf, GP, sch);
    k_colinv<<<dim3(17, cur), 256, 0, stream>>>(GP, TMP, sch);
    k_irfft_rows<<<cur * 32, 256, 0, stream>>>(TMP, out, s0);
  }
}

// Round 13
// 1653.393 us; speedup vs baseline: 6.1825x; 1.1300x over previous
//
#include <hip/hip_runtime.h>
#include <math.h>

#define S_TOT 64
#define CIN   3
#define CH    32
#define H     256
#define W     256
#define WF    129   // W/2+1
#define ZWF   136   // padded row stride for ZF/TMP (1088B = 17*64B aligned)
#define CSPLIT 8    // channel groups for column-forward pass
#define CPG    4    // channels per group (CSPLIT*CPG == CH)

typedef unsigned short u16;
typedef unsigned int   u32;
using bf16x8 = __attribute__((ext_vector_type(8))) short;
using f32x4  = __attribute__((ext_vector_type(4))) float;

__device__ inline float2 cmulf(float2 a, float2 b) {
  return make_float2(fmaf(a.x, b.x, -(a.y * b.y)), fmaf(a.x, b.y, a.y * b.x));
}

// round-to-nearest-even fp32 -> bf16
__device__ inline u16 rne_bf16(float f) {
  u32 u = __float_as_uint(f);
  u32 r = (u + 0x7FFFu + ((u >> 16) & 1u)) >> 16;
  return (u16)r;
}

// LDS XOR swizzle: relocate 16B blocks within 128B window by 64B-chunk index.
// Bijective; apply on BOTH write and read byte offsets. Keeps 16B alignment.
__device__ inline u32 swz(u32 a) { return a ^ (((a >> 6) & 7u) << 4); }

// ---------------- radix-4 Stockham FFT machinery (unchanged) ----------------
template<bool INV>
__device__ inline void r4_stage(const float2* __restrict__ src, float2* __restrict__ dst,
                                const float2* __restrict__ tw, int j, int t,
                                int stride, int off)
{
  int Ns   = 1 << (2 * t);
  int k    = j & (Ns - 1);
  int base = ((j >> (2 * t)) << (2 * t + 2)) | k;
  int ts   = 64 >> (2 * t);
  float2 a = src[(j      ) * stride + off];
  float2 b = src[(j +  64) * stride + off];
  float2 c = src[(j + 128) * stride + off];
  float2 d = src[(j + 192) * stride + off];
  float2 w1 = tw[k * ts], w2 = tw[2 * k * ts], w3 = tw[3 * k * ts];
  if (INV) { w1.y = -w1.y; w2.y = -w2.y; w3.y = -w3.y; }
  b = cmulf(b, w1); c = cmulf(c, w2); d = cmulf(d, w3);
  float ex = a.x + c.x, ey = a.y + c.y;
  float fx = a.x - c.x, fy = a.y - c.y;
  float gx = b.x + d.x, gy = b.y + d.y;
  float hx = b.x - d.x, hy = b.y - d.y;
  dst[(base         ) * stride + off] = make_float2(ex + gx, ey + gy);
  dst[(base + 2 * Ns) * stride + off] = make_float2(ex - gx, ey - gy);
  if (!INV) {
    dst[(base +     Ns) * stride + off] = make_float2(fx + hy, fy - hx);
    dst[(base + 3 * Ns) * stride + off] = make_float2(fx - hy, fy + hx);
  } else {
    dst[(base +     Ns) * stride + off] = make_float2(fx - hy, fy + hx);
    dst[(base + 3 * Ns) * stride + off] = make_float2(fx + hy, fy - hx);
  }
}

__device__ inline void build_tw(float2* tw, int tid) {
  if (tid < 192) {
    float fr = (float)tid * (1.0f / 128.0f);
    tw[tid] = make_float2(cospif(fr), -sinpif(fr));
  }
}

// ------ Kernel 0: pack w2 -> bf16 [tap][co][ci], once per launch ------
__global__ __launch_bounds__(256)
void k_packw(const float* __restrict__ w2, u16* __restrict__ wpack)
{
  int i = blockIdx.x * 256 + threadIdx.x;
  if (i < 9 * 32 * 32) {
    int t = i >> 10, rem = i & 1023, co = rem >> 5, ci = rem & 31;
    wpack[i] = rne_bf16(w2[((size_t)co * CH + ci) * 9 + t]);
  }
}

// ------ Kernel 1: conv1 (3->32, 3x3 SAME) + ReLU -> NHWC bf16 ------
__global__ __launch_bounds__(256)
void k_conv1(const float* __restrict__ z, const float* __restrict__ w1,
             const float* __restrict__ b1, u16* __restrict__ x1h, int s0)
{
  int tid = threadIdx.x;
  int co = tid & 31, xs = tid >> 5;
  int x  = blockIdx.x * 8 + xs;
  int y0 = blockIdx.y * 16;
  int s  = blockIdx.z;

  float wr[27];
  #pragma unroll
  for (int i = 0; i < 27; ++i) {
    int ci = i / 9, t = i - ci * 9;
    wr[i] = w1[(co * CIN + ci) * 9 + t];
  }
  float bias = b1[co];
  const float* zs = z + (size_t)(s0 + s) * CIN * H * W;

  float rb[3][9];   // [row slot][ci*3 + col]
  #pragma unroll
  for (int pre = 0; pre < 2; ++pre) {
    int yy = y0 - 1 + pre;
    #pragma unroll
    for (int ci = 0; ci < 3; ++ci)
      #pragma unroll
      for (int c = 0; c < 3; ++c) {
        int xx = x - 1 + c;
        float v = 0.f;
        if (yy >= 0 && yy < H && xx >= 0 && xx < W) v = zs[ci * (H*W) + yy * W + xx];
        rb[pre][ci * 3 + c] = v;
      }
  }
  u16* op = x1h + ((size_t)s * H * W) * CH;
  #pragma unroll
  for (int r = 0; r < 16; ++r) {
    int yy = y0 + r + 1;
    int sl2 = (r + 2) % 3;
    #pragma unroll
    for (int ci = 0; ci < 3; ++ci)
      #pragma unroll
      for (int c = 0; c < 3; ++c) {
        int xx = x - 1 + c;
        float v = 0.f;
        if (yy >= 0 && yy < H && xx >= 0 && xx < W) v = zs[ci * (H*W) + yy * W + xx];
        rb[sl2][ci * 3 + c] = v;
      }
    float acc = bias;
    #pragma unroll
    for (int ci = 0; ci < 3; ++ci)
      #pragma unroll
      for (int ky = 0; ky < 3; ++ky) {
        int sl = (r + ky) % 3;
        #pragma unroll
        for (int kx = 0; kx < 3; ++kx)
          acc = fmaf(rb[sl][ci * 3 + kx], wr[ci * 9 + ky * 3 + kx], acc);
      }
    acc = fmaxf(acc, 0.f);
    op[((size_t)(y0 + r) * W + x) * CH + co] = rne_bf16(acc);
  }
}

// ------ Kernel 2: conv2 via bf16 MFMA (K=ci per tap) + LRN + window ------
// Block = 256 thr = 4 waves; tile 8 rows x 16 cols x 32 co.
// B-fragments loaded per-ky from packed global weights (coalesced, L2-hit).
__global__ __launch_bounds__(256)
void k_conv2_mfma(const u16* __restrict__ x1h, const u16* __restrict__ wpack,
                  const float* __restrict__ b2, const float* __restrict__ cosw,
                  float* __restrict__ x2)
{
  __shared__ u16  tileh[10 * 18 * 32];   // [row][col][ci], swizzled, 11.5 KB
  __shared__ float xc[8 * 16 * 33];      // [row][px][co+pad] epilogue, 16.9 KB

  int tid = threadIdx.x;
  int x0 = blockIdx.x * 16;
  int y0 = blockIdx.y * 8;
  int s  = blockIdx.z;
  char* tb = (char*)tileh;

  // stage x1h tile rows y0-1..y0+8, cols x0-1..x0+16 (zero halo), u32 granularity
  const u16* xp = x1h + ((size_t)s * H * W) * CH;
  for (int i = tid; i < 10 * 18 * 16; i += 256) {
    int q = i & 15, rc = i >> 4;
    int col = rc % 18, row = rc / 18;
    int y = y0 - 1 + row, xg = x0 - 1 + col;
    u32 v = 0;
    if (y >= 0 && y < H && xg >= 0 && xg < W)
      v = *(const u32*)(xp + ((size_t)y * W + xg) * CH + q * 2);
    *(u32*)(tb + swz(((u32)(row * 18 + col) * 32 + (u32)q * 2) * 2)) = v;
  }
  __syncthreads();

  int wv = tid >> 6, l = tid & 63;
  int lm = l & 15, lg = l >> 4;
  int r0 = 2 * wv, r1 = 2 * wv + 1;      // pixel rows of this wave

  f32x4 acc[2][2];
  {
    float bv0 = b2[lm], bv1 = b2[16 + lm];
    acc[0][0] = f32x4{bv0, bv0, bv0, bv0};
    acc[0][1] = f32x4{bv1, bv1, bv1, bv1};
    acc[1][0] = acc[0][0];
    acc[1][1] = acc[0][1];
  }
  const bf16x8* wp8 = (const bf16x8*)wpack;   // fragment idx = (t*32+co)*4 + lg
  #pragma unroll
  for (int ky = 0; ky < 3; ++ky) {
    bf16x8 wf0[3], wf1[3];
    #pragma unroll
    for (int kx = 0; kx < 3; ++kx) {
      int t = ky * 3 + kx;
      wf0[kx] = wp8[((u32)t * 32 +      lm) * 4 + lg];
      wf1[kx] = wp8[((u32)t * 32 + 16 + lm) * 4 + lg];
    }
    #pragma unroll
    for (int kx = 0; kx < 3; ++kx) {
      bf16x8 a0 = *(bf16x8*)(tb + swz((((u32)(r0 + ky) * 18 + lm + kx) * 32 + (u32)lg * 8) * 2));
      bf16x8 a1 = *(bf16x8*)(tb + swz((((u32)(r1 + ky) * 18 + lm + kx) * 32 + (u32)lg * 8) * 2));
      acc[0][0] = __builtin_amdgcn_mfma_f32_16x16x32_bf16(a0, wf0[kx], acc[0][0], 0, 0, 0);
      acc[0][1] = __builtin_amdgcn_mfma_f32_16x16x32_bf16(a0, wf1[kx], acc[0][1], 0, 0, 0);
      acc[1][0] = __builtin_amdgcn_mfma_f32_16x16x32_bf16(a1, wf0[kx], acc[1][0], 0, 0, 0);
      acc[1][1] = __builtin_amdgcn_mfma_f32_16x16x32_bf16(a1, wf1[kx], acc[1][1], 0, 0, 0);
    }
  }
  // C layout: col(N=co) = lane&15, row(M=px) = (lane>>4)*4 + reg
  #pragma unroll
  for (int r = 0; r < 2; ++r)
    #pragma unroll
    for (int n = 0; n < 2; ++n)
      #pragma unroll
      for (int e = 0; e < 4; ++e) {
        int px = lg * 4 + e, co = n * 16 + lm, row = 2 * wv + r;
        xc[((row * 16 + px) * 33) + co] = acc[r][n][e];
      }
  __syncthreads();

  // LRN + cosine window: thread owns (pixel = tid>>1, co-half = tid&1)
  {
    int pl = tid >> 1, half = tid & 1;
    int row = pl >> 4, px = pl & 15;
    int co0 = half * 16;
    const float* xr = &xc[(row * 16 + px) * 33];
    float sq[20], vv[16];
    #pragma unroll
    for (int i = 0; i < 20; ++i) {
      int c = co0 - 2 + i;
      float u = (c >= 0 && c < 32) ? xr[c] : 0.f;
      if (i >= 2 && i < 18) vv[i - 2] = u;
      sq[i] = u * u;
    }
    int y = y0 + row, xg = x0 + px;
    float cw = cosw[y * W + xg];
    float* xo = &x2[(((size_t)s * CH + co0) * H + y) * W + xg];
    #pragma unroll
    for (int c = 0; c < 16; ++c) {
      float win = sq[c] + sq[c+1] + sq[c+2] + sq[c+3] + sq[c+4];
      float t = fmaf(2e-5f, win, 1.0f);
      float scale = __powf(t, -0.75f) * cw;
      xo[(size_t)c * (H * W)] = vv[c] * scale;
    }
  }
}

// ---------- Kernel 3: row rfft, 2 real rows packed per complex FFT ----------
__global__ __launch_bounds__(256)
void k_rfft_rows(const float* __restrict__ x2, float2* __restrict__ zf)
{
  __shared__ float2 bufA[4 * 256], bufB[4 * 256], tw[192];
  int tid = threadIdx.x;
  build_tw(tw, tid);
  int w = tid >> 6, j = tid & 63;
  int fid = blockIdx.x * 4 + w;
  size_t rowA = (size_t)fid * 2, rowB = rowA + 1;
  float2* A = bufA + w * 256;
  float2* B = bufB + w * 256;
  const float* pa = x2 + rowA * W;
  const float* pb = x2 + rowB * W;
  #pragma unroll
  for (int q = 0; q < 4; ++q) { int n = j + 64 * q; A[n] = make_float2(pa[n], pb[n]); }
  __syncthreads();
  #pragma unroll
  for (int t = 0; t < 4; ++t) {
    const float2* src = (t & 1) ? B : A;
    float2*       dst = (t & 1) ? A : B;
    r4_stage<false>(src, dst, tw, j, t, 1, 0);
    __syncthreads();
  }
  float2* op_a = zf + rowA * ZWF;
  float2* op_b = zf + rowB * ZWF;
  {
    int k = j, m = (256 - j) & 255;
    float2 zk = A[k], zm = A[m];
    op_a[k] = make_float2(0.5f * (zk.x + zm.x),  0.5f * (zk.y - zm.y));
    op_b[k] = make_float2(0.5f * (zk.y + zm.y), -0.5f * (zk.x - zm.x));
  }
  {
    int k = j + 64, m = 192 - j;
    float2 zk = A[k], zm = A[m];
    op_a[k] = make_float2(0.5f * (zk.x + zm.x),  0.5f * (zk.y - zm.y));
    op_b[k] = make_float2(0.5f * (zk.y + zm.y), -0.5f * (zk.x - zm.x));
  }
  if (j == 0) {
    float2 z128 = A[128];
    op_a[128] = make_float2(z128.x, 0.f);
    op_b[128] = make_float2(z128.y, 0.f);
  }
}

// ------ Kernel 4: forward column FFT (axis H) x wf + partial channel sum ------
__global__ __launch_bounds__(256)
void k_colfwd(const float2* __restrict__ zf, const float2* __restrict__ wf,
              float2* __restrict__ gpart, int sch)
{
  __shared__ float2 A[256 * 9], B[256 * 9], tw[192];
  int tid = threadIdx.x;
  build_tw(tw, tid);
  int tile = blockIdx.x, s = blockIdx.y, part = blockIdx.z;
  int col = tid & 7, jb = tid >> 3;
  int kx = tile * 8 + col;
  bool kv = (kx < WF);
  float2 gacc[8];
  #pragma unroll
  for (int i = 0; i < 8; ++i) gacc[i] = make_float2(0.f, 0.f);

  for (int cc = 0; cc < CPG; ++cc) {
    int c = part * CPG + cc;
    const float2* zp = zf + ((size_t)(s * CH + c) * H) * ZWF;
    __syncthreads();
    #pragma unroll
    for (int i = 0; i < 8; ++i) {
      int n = jb + 32 * i;
      float2 v = kv ? zp[(size_t)n * ZWF + kx] : make_float2(0.f, 0.f);
      A[n * 9 + col] = v;
    }
    __syncthreads();
    #pragma unroll
    for (int t = 0; t < 4; ++t) {
      const float2* src = (t & 1) ? B : A;
      float2*       dst = (t & 1) ? A : B;
      r4_stage<false>(src, dst, tw, jb,      t, 9, col);
      r4_stage<false>(src, dst, tw, jb + 32, t, 9, col);
      __syncthreads();
    }
    const float2* wp = wf + (size_t)c * H * WF;
    #pragma unroll
    for (int i = 0; i < 8; ++i) {
      int n = jb + 32 * i;
      float2 zv = A[n * 9 + col];
      float2 wv = kv ? wp[(size_t)n * WF + kx] : make_float2(0.f, 0.f);
      gacc[i].x = fmaf( wv.x, zv.x, gacc[i].x);
      gacc[i].y = fmaf(-wv.y, zv.y, gacc[i].y);
    }
  }
  if (kv) {
    float2* gp = gpart + ((size_t)(part * sch + s) * H) * ZWF;
    #pragma unroll
    for (int i = 0; i < 8; ++i) { int n = jb + 32 * i; gp[(size_t)n * ZWF + kx] = gacc[i]; }
  }
}

// ------ Kernel 5: sum partials + inverse column FFT (axis H) -> TMP ------
__global__ __launch_bounds__(256)
void k_colinv(const float2* __restrict__ gpart, float2* __restrict__ tmp, int sch)
{
  __shared__ float2 A[256 * 9], B[256 * 9], tw[192];
  int tid = threadIdx.x;
  build_tw(tw, tid);
  int tile = blockIdx.x, s = blockIdx.y;
  int col = tid & 7, jb = tid >> 3;
  int kx = tile * 8 + col;
  bool kv = (kx < WF);
  #pragma unroll
  for (int i = 0; i < 8; ++i) {
    int n = jb + 32 * i;
    float2 acc = make_float2(0.f, 0.f);
    if (kv) {
      #pragma unroll
      for (int p = 0; p < CSPLIT; ++p) {
        float2 v = gpart[((size_t)(p * sch + s) * H + n) * ZWF + kx];
        acc.x += v.x; acc.y += v.y;
      }
    }
    A[n * 9 + col] = acc;
  }
  __syncthreads();
  #pragma unroll
  for (int t = 0; t < 4; ++t) {
    const float2* src = (t & 1) ? B : A;
    float2*       dst = (t & 1) ? A : B;
    r4_stage<true>(src, dst, tw, jb,      t, 9, col);
    r4_stage<true>(src, dst, tw, jb + 32, t, 9, col);
    __syncthreads();
  }
  if (kv) {
    float2* tp = tmp + (size_t)s * H * ZWF;
    #pragma unroll
    for (int i = 0; i < 8; ++i) { int n = jb + 32 * i; tp[(size_t)n * ZWF + kx] = A[n * 9 + col]; }
  }
}

// ------ Kernel 6: row irfft, 2 output rows packed per inverse complex FFT ------
__global__ __launch_bounds__(256)
void k_irfft_rows(const float2* __restrict__ tmp, float* __restrict__ out, int s0)
{
  __shared__ float2 bufA[4 * 256], bufB[4 * 256], tw[192];
  int tid = threadIdx.x;
  build_tw(tw, tid);
  int w = tid >> 6, j = tid & 63;
  int fid = blockIdx.x * 4 + w;
  int s = fid >> 7, q = fid & 127;
  int hA = 2 * q, hB = hA + 1;
  const float2* ta = tmp + ((size_t)s * H + hA) * ZWF;
  const float2* tb = tmp + ((size_t)s * H + hB) * ZWF;
  float2* A = bufA + w * 256;
  float2* B = bufB + w * 256;
  {
    float2 a0 = ta[j], b0 = tb[j];
    if (j == 0) { a0.y = 0.f; b0.y = 0.f; }
    A[j] = make_float2(a0.x - b0.y, a0.y + b0.x);
    float2 a1 = ta[j + 64], b1 = tb[j + 64];
    A[j + 64] = make_float2(a1.x - b1.y, a1.y + b1.x);
    float2 a2 = ta[128 - j], b2 = tb[128 - j];
    if (j == 0) { a2.y = 0.f; b2.y = 0.f; }
    a2.y = -a2.y; b2.y = -b2.y;
    A[j + 128] = make_float2(a2.x - b2.y, a2.y + b2.x);
    float2 a3 = ta[64 - j], b3 = tb[64 - j];
    a3.y = -a3.y; b3.y = -b3.y;
    A[j + 192] = make_float2(a3.x - b3.y, a3.y + b3.x);
  }
  __syncthreads();
  #pragma unroll
  for (int t = 0; t < 4; ++t) {
    const float2* src = (t & 1) ? B : A;
    float2*       dst = (t & 1) ? A : B;
    r4_stage<true>(src, dst, tw, j, t, 1, 0);
    __syncthreads();
  }
  const float sc = 1.0f / 65536.0f;
  float* oa = out + ((size_t)(s0 + s) * H + hA) * W;
  float* ob = out + ((size_t)(s0 + s) * H + hB) * W;
  #pragma unroll
  for (int q4 = 0; q4 < 4; ++q4) {
    int n = j + 64 * q4;
    float2 zv = A[n];
    oa[n] = zv.x * sc;
    ob[n] = zv.y * sc;
  }
}

extern "C" void kernel_launch(void* const* d_in, const int* in_sizes, int n_in,
                              void* d_out, int out_size, void* d_ws, size_t ws_size,
                              hipStream_t stream)
{
  const float*  z    = (const float*)d_in[0];
  const float*  cosw = (const float*)d_in[1];
  const float2* wf   = (const float2*)d_in[2];
  const float*  w1   = (const float*)d_in[3];
  const float*  b1   = (const float*)d_in[4];
  const float*  w2   = (const float*)d_in[5];
  const float*  b2   = (const float*)d_in[6];
  float* out = (float*)d_out;

  // fixed workspace head: packed bf16 weights (18432 B, padded to 32 KB)
  char* p = (char*)d_ws;
  u16* WPK = (u16*)p;  p += 32768;

  // per-sample workspace bytes
  size_t x1hb = (size_t)H * W * CH * 2;             // conv1 out, NHWC bf16
  size_t x2b  = (size_t)CH * H * W * 4;             // conv2 out, planar fp32
  size_t zfb  = (size_t)CH * H * ZWF * 8;           // row-fft out (padded)
  size_t gpb  = (size_t)CSPLIT * H * ZWF * 8;       // partial G
  size_t tpb  = (size_t)H * ZWF * 8;                // after inverse col fft
  size_t per  = x1hb + x2b + zfb + gpb + tpb;

  int sch = (int)((ws_size - 32768) / per);
  if (sch > S_TOT) sch = S_TOT;
  if (sch < 1) sch = 1;

  u16*    X1H = (u16*)p;    p += x1hb * sch;
  float*  X2  = (float*)p;  p += x2b * sch;
  float2* ZF  = (float2*)p; p += zfb * sch;
  float2* GP  = (float2*)p; p += gpb * sch;
  float2* TMP = (float2*)p; p += tpb * sch;

  k_packw<<<36, 256, 0, stream>>>(w2, WPK);

  for (int s0 = 0; s0 < S_TOT; s0 += sch) {
    int cur = S_TOT - s0; if (cur > sch) cur = sch;
    k_conv1<<<dim3(W/8, H/16, cur), 256, 0, stream>>>(z, w1, b1, X1H, s0);
    k_conv2_mfma<<<dim3(W/16, H/8, cur), 256, 0, stream>>>(X1H, WPK, b2, cosw, X2);
    k_rfft_rows<<<cur * 1024, 256, 0, stream>>>(X2, ZF);
    k_colfwd<<<dim3(17, cur, CSPLIT), 256, 0, stream>>>(ZF, wf, GP, sch);
    k_colinv<<<dim3(17, cur), 256, 0, stream>>>(GP, TMP, sch);
    k_irfft_rows<<<cur * 32, 256, 0, stream>>>(TMP, out, s0);
  }
}